// Round 1
// baseline (5524.504 us; speedup 1.0000x reference)
//
#include <hip/hip_runtime.h>

#define BB 16384
#define KK 30
#define NLAYER 90
#define VLEN 60
#define ZLEN 240
#define INLEN 150
#define ROWS 32
#define PAD 36   // LDS row stride in floats (16B-aligned, breaks power-of-2)

// LDS layout (all [feature][row] transposed so GEMM reads are lane-broadcast):
//   cT rows 0..29   = Hr
//   cT rows 30..89  = v
//   cT rows 90..119 = t
//   cT rows 120..149= tH
__global__ __launch_bounds__(256, 2)
void detnet_kernel(const float* __restrict__ Hr,
                   const float* __restrict__ HH,
                   const float* __restrict__ W1,
                   const float* __restrict__ b1,
                   const float* __restrict__ W2,
                   const float* __restrict__ b2,
                   const float* __restrict__ W3,
                   const float* __restrict__ b3,
                   const float* __restrict__ kappa,
                   float* __restrict__ out)
{
    __shared__ float cT[INLEN][PAD];
    __shared__ float zT[ZLEN][PAD];
    __shared__ float ttT[KK][PAD];

    const int tid = threadIdx.x;
    const int b0 = blockIdx.x * ROWS;

    // ---- init: zero state LDS, load Hr transposed ----
    for (int i = tid; i < INLEN * PAD; i += 256) (&cT[0][0])[i] = 0.f;
    for (int i = tid; i < KK * PAD;   i += 256) (&ttT[0][0])[i] = 0.f;
    __syncthreads();
    for (int idx = tid; idx < ROWS * KK; idx += 256) {
        int r = idx / KK, k = idx - r * KK;
        cT[k][r] = Hr[(size_t)(b0 + r) * KK + k];
    }
    __syncthreads();

    for (int l = 0; l < NLAYER; ++l) {
        // ---- phase A: tH = t . HH  (per-row 30x30 matvec) ----
        {
            const int r = tid >> 3, sub = tid & 7;
            const float* hh = HH + (size_t)(b0 + r) * (KK * KK);
            const bool has3 = (sub + 24) < KK;
            float a0 = 0.f, a1 = 0.f, a2 = 0.f, a3 = 0.f;
            #pragma unroll 5
            for (int k = 0; k < KK; ++k) {
                float tk = cT[90 + k][r];
                const float* hrow = hh + k * KK + sub;
                a0 += tk * hrow[0];
                a1 += tk * hrow[8];
                a2 += tk * hrow[16];
                if (has3) a3 += tk * hrow[24];
            }
            cT[120 + sub][r] = a0;
            cT[128 + sub][r] = a1;
            cT[136 + sub][r] = a2;
            if (has3) cT[144 + sub][r] = a3;
        }
        __syncthreads();

        // ---- phase B: z = relu(concat @ W1^T + b1), stored transposed ----
        if (tid < ZLEN) {
            const int c = tid;
            const float* w = W1 + (size_t)l * ZLEN * INLEN + (size_t)c * INLEN;
            float acc[ROWS];
            const float bias = b1[l * ZLEN + c];
            #pragma unroll
            for (int r = 0; r < ROWS; ++r) acc[r] = bias;
            const float2* w2p = (const float2*)w;   // 600c bytes: 8B aligned
            for (int kk2 = 0; kk2 < INLEN / 2; ++kk2) {
                float2 wv = w2p[kk2];
                const int k0 = kk2 * 2;
                {
                    const float4* x = (const float4*)&cT[k0][0];
                    #pragma unroll
                    for (int i = 0; i < 8; ++i) {
                        float4 xv = x[i];
                        acc[4*i+0] += wv.x * xv.x; acc[4*i+1] += wv.x * xv.y;
                        acc[4*i+2] += wv.x * xv.z; acc[4*i+3] += wv.x * xv.w;
                    }
                }
                {
                    const float4* x = (const float4*)&cT[k0 + 1][0];
                    #pragma unroll
                    for (int i = 0; i < 8; ++i) {
                        float4 xv = x[i];
                        acc[4*i+0] += wv.y * xv.x; acc[4*i+1] += wv.y * xv.y;
                        acc[4*i+2] += wv.y * xv.z; acc[4*i+3] += wv.y * xv.w;
                    }
                }
            }
            #pragma unroll
            for (int i = 0; i < 8; ++i) {
                float4 o;
                o.x = fmaxf(acc[4*i+0], 0.f); o.y = fmaxf(acc[4*i+1], 0.f);
                o.z = fmaxf(acc[4*i+2], 0.f); o.w = fmaxf(acc[4*i+3], 0.f);
                *(float4*)&zT[c][4*i] = o;
            }
        }
        __syncthreads();

        // ---- phase C: dtt = z@W2^T + b2 ; dv = z@W3^T + b3 ; state updates ----
        if (tid < 180) {
            int c, r0;
            if (tid < 90) { c = tid; r0 = 0; } else { c = tid - 90; r0 = 16; }
            const bool isT = (c < KK);
            const float* w;
            float bias;
            if (isT) { w = W2 + (size_t)l * KK * ZLEN + (size_t)c * ZLEN;          bias = b2[l * KK + c]; }
            else     { w = W3 + (size_t)l * VLEN * ZLEN + (size_t)(c - KK) * ZLEN; bias = b3[l * VLEN + (c - KK)]; }
            float acc[16];
            #pragma unroll
            for (int r = 0; r < 16; ++r) acc[r] = bias;
            const float4* w4 = (const float4*)w;    // 960c bytes: 16B aligned
            for (int kc = 0; kc < ZLEN / 4; ++kc) {
                float4 wv = w4[kc];
                const int k0 = kc * 4;
                #pragma unroll
                for (int q = 0; q < 4; ++q) {
                    float wq = (q == 0) ? wv.x : (q == 1) ? wv.y : (q == 2) ? wv.z : wv.w;
                    const float4* x = (const float4*)&zT[k0 + q][r0];
                    #pragma unroll
                    for (int i = 0; i < 4; ++i) {
                        float4 xv = x[i];
                        acc[4*i+0] += wq * xv.x; acc[4*i+1] += wq * xv.y;
                        acc[4*i+2] += wq * xv.z; acc[4*i+3] += wq * xv.w;
                    }
                }
            }
            if (isT) {
                const float kap = kappa[l];
                const float inv = 1.0f / fabsf(kap);
                #pragma unroll
                for (int r = 0; r < 16; ++r) {
                    float tt = ttT[c][r0 + r] + acc[r];
                    ttT[c][r0 + r] = tt;
                    float tn = -1.0f + fmaxf(tt + kap, 0.f) * inv - fmaxf(tt - kap, 0.f) * inv;
                    cT[90 + c][r0 + r] = tn;
                }
            } else {
                #pragma unroll
                for (int r = 0; r < 16; ++r) cT[c][r0 + r] += acc[r];  // v rows are 30..89 == c
            }
        }
        __syncthreads();

        // ---- phase D: coalesced output write of t_new ----
        {
            float* o = out + (size_t)l * (BB * KK);
            for (int idx = tid; idx < ROWS * KK; idx += 256) {
                int r = idx / KK, k = idx - r * KK;
                o[(size_t)(b0 + r) * KK + k] = cT[90 + k][r];
            }
        }
        // no barrier needed: next phase A only reads t rows (read-read), and
        // the next write to t/v/tt rows is behind two barriers.
    }
}

extern "C" void kernel_launch(void* const* d_in, const int* in_sizes, int n_in,
                              void* d_out, int out_size, void* d_ws, size_t ws_size,
                              hipStream_t stream) {
    const float* Hr = (const float*)d_in[0];
    const float* HH = (const float*)d_in[1];
    const float* W1 = (const float*)d_in[2];
    const float* b1 = (const float*)d_in[3];
    const float* W2 = (const float*)d_in[4];
    const float* b2 = (const float*)d_in[5];
    const float* W3 = (const float*)d_in[6];
    const float* b3 = (const float*)d_in[7];
    const float* kp = (const float*)d_in[8];
    float* out = (float*)d_out;
    detnet_kernel<<<dim3(BB / ROWS), dim3(256), 0, stream>>>(
        Hr, HH, W1, b1, W2, b2, W3, b3, kp, out);
}

// Round 2
// 5405.933 us; speedup vs baseline: 1.0219x; 1.0219x over previous
//
#include <hip/hip_runtime.h>

#define BB 16384
#define KK 30
#define NLAYER 90
#define VLEN 60
#define ZLEN 240
#define INLEN 150
#define ROWS 16
#define PAD 20          // floats per LDS row: 16 data + 4 pad, 16B-aligned rows
#define NBLK (BB / ROWS)

// Transposed weight layouts in d_ws (coalesced loads: lane c reads element c):
//   W1T  [l][k][c] : l<90, k<150, c<240   (from W1 [l][c][k])
//   W23T [l][k][c] : l<90, k<240, c<90    (c<30: W2 row c ; c>=30: W3 row c-30)
#define W1T_ELEMS  (90 * 150 * 240)
#define W23T_ELEMS (90 * 240 * 90)
#define WS_NEEDED  ((size_t)(W1T_ELEMS + W23T_ELEMS) * 4)

__global__ void prep_transpose(const float* __restrict__ W1,
                               const float* __restrict__ W2,
                               const float* __restrict__ W3,
                               float* __restrict__ W1T,
                               float* __restrict__ W23T)
{
    int idx = blockIdx.x * 256 + threadIdx.x;
    if (idx < W1T_ELEMS) {
        int l = idx / (150 * 240);
        int r = idx - l * (150 * 240);
        int k = r / 240;
        int c = r - k * 240;
        W1T[idx] = W1[((size_t)l * 240 + c) * 150 + k];
    }
    if (idx < W23T_ELEMS) {
        int l = idx / (240 * 90);
        int r = idx - l * (240 * 90);
        int k = r / 90;
        int c = r - k * 90;
        float v;
        if (c < 30) v = W2[((size_t)l * 30 + c) * 240 + k];
        else        v = W3[((size_t)l * 60 + (c - 30)) * 240 + k];
        W23T[idx] = v;
    }
}

// LDS rows (all [feature][row], lane-invariant addresses => broadcast reads):
//   cT rows 0..29   = Hr ; 30..89 = v ; 90..119 = t ; 120..149 = tH
__global__ __launch_bounds__(256, 4)
void detnet_kernel(const float* __restrict__ Hr,
                   const float* __restrict__ HH,
                   const float* __restrict__ W1,
                   const float* __restrict__ b1,
                   const float* __restrict__ W2,
                   const float* __restrict__ b2,
                   const float* __restrict__ W3,
                   const float* __restrict__ b3,
                   const float* __restrict__ kappa,
                   const float* __restrict__ W1T,
                   const float* __restrict__ W23T,
                   float* __restrict__ out,
                   int useT)
{
    __shared__ float cT[INLEN][PAD];
    __shared__ float zT[ZLEN][PAD];

    const int tid = threadIdx.x;
    const int b0 = blockIdx.x * ROWS;

    // per-thread t_tilde state for phase C (thread->(c, row-slice) mapping is
    // stable across layers, so registers are safe)
    float tt[8];
    #pragma unroll
    for (int i = 0; i < 8; ++i) tt[i] = 0.f;

    for (int i = tid; i < INLEN * PAD; i += 256) (&cT[0][0])[i] = 0.f;
    __syncthreads();
    for (int idx = tid; idx < ROWS * KK; idx += 256) {
        int r = idx / KK, k = idx - r * KK;
        cT[k][r] = Hr[(size_t)(b0 + r) * KK + k];
    }
    __syncthreads();

    for (int l = 0; l < NLAYER; ++l) {
        // ---- phase A: tH = t . HH (per-row 30x30 matvec), float2 over j ----
        {
            const int r = tid >> 4;        // 0..15
            const int s = tid & 15;        // 0..15, active s<15 (j = 2s, 2s+1)
            if (s < 15) {
                const float* hh = HH + (size_t)(b0 + r) * (KK * KK) + 2 * s;
                float ax = 0.f, ay = 0.f;
                #pragma unroll 6
                for (int k = 0; k < KK; ++k) {
                    float tk = cT[90 + k][r];
                    float2 h = *(const float2*)(hh + k * KK);
                    ax += tk * h.x;
                    ay += tk * h.y;
                }
                cT[120 + 2 * s][r] = ax;
                cT[121 + 2 * s][r] = ay;
            }
        }
        __syncthreads();

        // ---- phase B: z = relu(concat @ W1^T + b1), stored transposed ----
        if (tid < ZLEN) {
            const int c = tid;
            float acc[16];
            const float bias = b1[l * ZLEN + c];
            #pragma unroll
            for (int r = 0; r < 16; ++r) acc[r] = bias;

            if (useT) {
                const float* w = W1T + (size_t)l * (INLEN * ZLEN) + c;
                #pragma unroll 2
                for (int k = 0; k < INLEN; ++k) {
                    float wk = w[k * ZLEN];          // coalesced across lanes
                    const float4* x = (const float4*)&cT[k][0];
                    float4 x0 = x[0], x1 = x[1], x2 = x[2], x3 = x[3];
                    acc[0]  += wk * x0.x; acc[1]  += wk * x0.y;
                    acc[2]  += wk * x0.z; acc[3]  += wk * x0.w;
                    acc[4]  += wk * x1.x; acc[5]  += wk * x1.y;
                    acc[6]  += wk * x1.z; acc[7]  += wk * x1.w;
                    acc[8]  += wk * x2.x; acc[9]  += wk * x2.y;
                    acc[10] += wk * x2.z; acc[11] += wk * x2.w;
                    acc[12] += wk * x3.x; acc[13] += wk * x3.y;
                    acc[14] += wk * x3.z; acc[15] += wk * x3.w;
                }
            } else {
                const float2* w2p = (const float2*)(W1 + (size_t)l * ZLEN * INLEN + (size_t)c * INLEN);
                for (int kk2 = 0; kk2 < INLEN / 2; ++kk2) {
                    float2 wv = w2p[kk2];
                    const int k0 = kk2 * 2;
                    #pragma unroll
                    for (int q = 0; q < 2; ++q) {
                        float wq = q ? wv.y : wv.x;
                        const float4* x = (const float4*)&cT[k0 + q][0];
                        #pragma unroll
                        for (int i = 0; i < 4; ++i) {
                            float4 xv = x[i];
                            acc[4*i+0] += wq * xv.x; acc[4*i+1] += wq * xv.y;
                            acc[4*i+2] += wq * xv.z; acc[4*i+3] += wq * xv.w;
                        }
                    }
                }
            }
            #pragma unroll
            for (int i = 0; i < 4; ++i) {
                float4 o;
                o.x = fmaxf(acc[4*i+0], 0.f); o.y = fmaxf(acc[4*i+1], 0.f);
                o.z = fmaxf(acc[4*i+2], 0.f); o.w = fmaxf(acc[4*i+3], 0.f);
                *(float4*)&zT[c][4*i] = o;
            }
        }
        __syncthreads();

        // ---- phase C: dtt = z@W2^T + b2 ; dv = z@W3^T + b3 ; state update ----
        if (tid < 180) {
            const int c  = (tid < 90) ? tid : tid - 90;   // 0..89
            const int r0 = (tid < 90) ? 0 : 8;            // row slice
            const bool isT = (c < KK);
            float bias;
            if (isT) bias = b2[l * KK + c];
            else     bias = b3[l * VLEN + (c - KK)];
            float acc[8];
            #pragma unroll
            for (int i = 0; i < 8; ++i) acc[i] = bias;

            if (useT) {
                const float* w = W23T + (size_t)l * (240 * 90) + c;
                #pragma unroll 2
                for (int k = 0; k < ZLEN; ++k) {
                    float wk = w[k * 90];                // coalesced across lanes
                    const float4* x = (const float4*)&zT[k][r0];
                    float4 z0 = x[0], z1 = x[1];
                    acc[0] += wk * z0.x; acc[1] += wk * z0.y;
                    acc[2] += wk * z0.z; acc[3] += wk * z0.w;
                    acc[4] += wk * z1.x; acc[5] += wk * z1.y;
                    acc[6] += wk * z1.z; acc[7] += wk * z1.w;
                }
            } else {
                const float* wrow;
                if (isT) wrow = W2 + (size_t)l * KK * ZLEN + (size_t)c * ZLEN;
                else     wrow = W3 + (size_t)l * VLEN * ZLEN + (size_t)(c - KK) * ZLEN;
                const float4* w4 = (const float4*)wrow;
                for (int kc = 0; kc < ZLEN / 4; ++kc) {
                    float4 wv = w4[kc];
                    const int k0 = kc * 4;
                    #pragma unroll
                    for (int q = 0; q < 4; ++q) {
                        float wq = (q == 0) ? wv.x : (q == 1) ? wv.y : (q == 2) ? wv.z : wv.w;
                        const float4* x = (const float4*)&zT[k0 + q][r0];
                        float4 z0 = x[0], z1 = x[1];
                        acc[0] += wq * z0.x; acc[1] += wq * z0.y;
                        acc[2] += wq * z0.z; acc[3] += wq * z0.w;
                        acc[4] += wq * z1.x; acc[5] += wq * z1.y;
                        acc[6] += wq * z1.z; acc[7] += wq * z1.w;
                    }
                }
            }

            if (isT) {
                const float kap = kappa[l];
                const float inv = 1.0f / fabsf(kap);
                #pragma unroll
                for (int i = 0; i < 8; ++i) {
                    float t2 = tt[i] + acc[i];
                    tt[i] = t2;
                    float tn = -1.0f + fmaxf(t2 + kap, 0.f) * inv - fmaxf(t2 - kap, 0.f) * inv;
                    cT[90 + c][r0 + i] = tn;
                }
            } else {
                #pragma unroll
                for (int i = 0; i < 8; ++i) cT[c][r0 + i] += acc[i];  // v rows 30..89 == c
            }
        }
        __syncthreads();

        // ---- phase D: coalesced output write of t_new ----
        {
            float* o = out + (size_t)l * (BB * KK);
            for (int idx = tid; idx < ROWS * KK; idx += 256) {
                int r = idx / KK, k = idx - r * KK;
                o[(size_t)(b0 + r) * KK + k] = cT[90 + k][r];
            }
        }
        // no barrier: next phase A only reads t rows (read-read); first write
        // to t/v rows is behind two barriers.
    }
}

extern "C" void kernel_launch(void* const* d_in, const int* in_sizes, int n_in,
                              void* d_out, int out_size, void* d_ws, size_t ws_size,
                              hipStream_t stream) {
    const float* Hr = (const float*)d_in[0];
    const float* HH = (const float*)d_in[1];
    const float* W1 = (const float*)d_in[2];
    const float* b1 = (const float*)d_in[3];
    const float* W2 = (const float*)d_in[4];
    const float* b2 = (const float*)d_in[5];
    const float* W3 = (const float*)d_in[6];
    const float* b3 = (const float*)d_in[7];
    const float* kp = (const float*)d_in[8];
    float* out = (float*)d_out;

    int useT = (d_ws != nullptr && ws_size >= WS_NEEDED) ? 1 : 0;
    float* W1T  = (float*)d_ws;
    float* W23T = W1T + W1T_ELEMS;
    if (useT) {
        prep_transpose<<<dim3((W1T_ELEMS + 255) / 256), dim3(256), 0, stream>>>(
            W1, W2, W3, W1T, W23T);
    }
    detnet_kernel<<<dim3(NBLK), dim3(256), 0, stream>>>(
        Hr, HH, W1, b1, W2, b2, W3, b3, kp, W1T, W23T, out, useT);
}

// Round 4
// 2366.030 us; speedup vs baseline: 2.3349x; 2.2848x over previous
//
#include <hip/hip_runtime.h>

typedef unsigned short u16;
typedef float    f32x4  __attribute__((ext_vector_type(4)));
typedef _Float16 f16x8  __attribute__((ext_vector_type(8)));
typedef short    short8 __attribute__((ext_vector_type(8)));

#define BB 16384
#define KK 30
#define NLAYER 90
#define ROWS 32
#define NBLK (BB / ROWS)

#define NT1 16        // phase-B N-tiles (240 -> 256 padded)
#define KS1 5         // phase-B K-steps (150 -> 160 padded)
#define NT2 6         // phase-C N-tiles (90 -> 96 padded)
#define KS2 8         // phase-C K-steps (240 -> 256 padded)

#define SZ1  (NLAYER * NT1 * KS1 * 512)   // 3,686,400 u16 per plane
#define SZ23 (NLAYER * NT2 * KS2 * 512)   // 2,211,840 u16 per plane
#define WS_NEEDED ((size_t)4 * (SZ1 + SZ23) + (size_t)4 * (NLAYER * 256 + NLAYER * 96))

#define A_STRIDE 168   // 160 k + 8 pad (u16)
#define Z_STRIDE 264   // 256 k + 8 pad (u16)
#define TO_STRIDE 33

#define MFMA(a, b, c) __builtin_amdgcn_mfma_f32_16x16x32_f16((a), (b), (c), 0, 0, 0)

__device__ __forceinline__ void splitf(float x, u16& hi, u16& lo) {
    _Float16 h = (_Float16)x;
    _Float16 l = (_Float16)(x - (float)h);
    hi = __builtin_bit_cast(u16, h);
    lo = __builtin_bit_cast(u16, l);
}
__device__ __forceinline__ f16x8 ldfrag(const u16* p) {
    return __builtin_bit_cast(f16x8, *(const short8*)p);
}

// ---------------- prep: weights -> MFMA fragment layout (split fp16) -------
// W1F  idx = (((l*16+nt)*5+ks)*64+lane)*8+j ; k=ks*32+(lane>>4)*8+j ; n=nt*16+(lane&15)
// W23F idx = (((l*6+nt)*8+ks)*64+lane)*8+j  ; same k/n decode; n<30->W2 else W3
__global__ void prep(const float* __restrict__ W1, const float* __restrict__ W2,
                     const float* __restrict__ W3, const float* __restrict__ b1,
                     const float* __restrict__ b2, const float* __restrict__ b3,
                     u16* __restrict__ W1Fhi, u16* __restrict__ W1Flo,
                     u16* __restrict__ W23Fhi, u16* __restrict__ W23Flo,
                     float* __restrict__ b1p, float* __restrict__ b23p)
{
    int idx = blockIdx.x * 256 + threadIdx.x;
    if (idx < SZ1) {
        int j = idx & 7, lane = (idx >> 3) & 63;
        int r = idx >> 9, ks = r % 5; r /= 5;
        int nt = r % 16, l = r / 16;
        int k = ks * 32 + (lane >> 4) * 8 + j;
        int n = nt * 16 + (lane & 15);
        float wv = (k < 150 && n < 240) ? W1[((size_t)l * 240 + n) * 150 + k] : 0.f;
        splitf(wv, W1Fhi[idx], W1Flo[idx]);
    }
    if (idx < SZ23) {
        int j = idx & 7, lane = (idx >> 3) & 63;
        int r = idx >> 9, ks = r % 8; r /= 8;
        int nt = r % 6, l = r / 6;
        int k = ks * 32 + (lane >> 4) * 8 + j;
        int n = nt * 16 + (lane & 15);
        float wv = 0.f;
        if (k < 240) {
            if (n < 30)      wv = W2[((size_t)l * 30 + n) * 240 + k];
            else if (n < 90) wv = W3[((size_t)l * 60 + (n - 30)) * 240 + k];
        }
        splitf(wv, W23Fhi[idx], W23Flo[idx]);
    }
    if (idx < NLAYER * 256) {
        int l = idx >> 8, c = idx & 255;
        b1p[idx] = (c < 240) ? b1[l * 240 + c] : 0.f;
    }
    if (idx < NLAYER * 96) {
        int l = idx / 96, c = idx % 96;
        b23p[idx] = (c < 30) ? b2[l * 30 + c] : (c < 90 ? b3[l * 60 + (c - 30)] : 0.f);
    }
}

// ---------------- main persistent kernel ------------------------------------
// concat LDS cols: 0..29 Hr | 30..89 v | 90..119 t | 120..149 tH | 150..159 zero
__global__ __launch_bounds__(256, 2)
void detnet_kernel(const float* __restrict__ Hr, const float* __restrict__ HH,
                   const float* __restrict__ kappa,
                   const u16* __restrict__ W1Fhi, const u16* __restrict__ W1Flo,
                   const u16* __restrict__ W23Fhi, const u16* __restrict__ W23Flo,
                   const float* __restrict__ b1p, const float* __restrict__ b23p,
                   float* __restrict__ out)
{
    __shared__ u16 aT_hi[ROWS][A_STRIDE], aT_lo[ROWS][A_STRIDE];
    __shared__ u16 zT_hi[ROWS][Z_STRIDE], zT_lo[ROWS][Z_STRIDE];
    __shared__ float tOut[ROWS][TO_STRIDE];

    const int tid  = threadIdx.x;
    const int b0   = blockIdx.x * ROWS;
    const int w    = tid >> 6;
    const int lane = tid & 63;
    const int h    = lane >> 4;
    const int q    = lane & 15;

    // phase-C persistent state: [tile-slot][m][reg] = t_tilde (t-cols) or v (v-cols)
    float st[2][2][4];
    #pragma unroll
    for (int a = 0; a < 2; ++a)
        #pragma unroll
        for (int m = 0; m < 2; ++m)
            #pragma unroll
            for (int r = 0; r < 4; ++r) st[a][m][r] = 0.f;

    const int nt0    = (w < 2) ? 2 * w : w + 2;   // phase-C tiles: {0,1},{2,3},{4},{5}
    const int nt_cnt = (w < 2) ? 2 : 1;

    // ---- init LDS ----
    for (int i = tid; i < ROWS * A_STRIDE; i += 256) { (&aT_hi[0][0])[i] = 0; (&aT_lo[0][0])[i] = 0; }
    for (int i = tid; i < ROWS * Z_STRIDE; i += 256) { (&zT_hi[0][0])[i] = 0; (&zT_lo[0][0])[i] = 0; }
    for (int i = tid; i < ROWS * TO_STRIDE; i += 256) (&tOut[0][0])[i] = 0.f;
    __syncthreads();
    for (int i = tid; i < ROWS * KK; i += 256) {
        int r = i / KK, k = i - r * KK;
        splitf(Hr[(size_t)(b0 + r) * KK + k], aT_hi[r][k], aT_lo[r][k]);
    }
    __syncthreads();

    for (int l = 0; l < NLAYER; ++l) {
        // ---- phase D (prev layer) : NT store of t ----
        if (l > 0 && tid < 240) {
            f32x4 o;
            int e = tid * 4;
            #pragma unroll
            for (int i = 0; i < 4; ++i) {
                int ee = e + i, r = ee / 30, k2 = ee - 30 * r;
                o[i] = tOut[r][k2];
            }
            __builtin_nontemporal_store(o, (f32x4*)(out + ((size_t)(l - 1) * BB + b0) * KK + e));
        }

        // ---- phase A : tH = t . HH (fp32 VALU), split-write to aT ----
        if (l > 0) {
            const int r = tid >> 3, s = tid & 7;
            const float* hh = HH + (size_t)(b0 + r) * (KK * KK);
            const bool two = (s < 7);
            float a0 = 0.f, a1 = 0.f, c0 = 0.f, c1 = 0.f;
            #pragma unroll 6
            for (int k = 0; k < KK; ++k) {
                float tk = tOut[r][k];
                const float* rowp = hh + k * KK;
                float2 u = *(const float2*)(rowp + 2 * s);
                a0 += tk * u.x; a1 += tk * u.y;
                if (two) {
                    float2 v2 = *(const float2*)(rowp + 16 + 2 * s);
                    c0 += tk * v2.x; c1 += tk * v2.y;
                }
            }
            u16 h0, l0, h1, l1;
            splitf(a0, h0, l0); splitf(a1, h1, l1);
            *(unsigned int*)&aT_hi[r][120 + 2 * s] = (unsigned int)h0 | ((unsigned int)h1 << 16);
            *(unsigned int*)&aT_lo[r][120 + 2 * s] = (unsigned int)l0 | ((unsigned int)l1 << 16);
            if (two) {
                splitf(c0, h0, l0); splitf(c1, h1, l1);
                *(unsigned int*)&aT_hi[r][136 + 2 * s] = (unsigned int)h0 | ((unsigned int)h1 << 16);
                *(unsigned int*)&aT_lo[r][136 + 2 * s] = (unsigned int)l0 | ((unsigned int)l1 << 16);
            }
        }
        __syncthreads();

        // ---- phase B : z = relu(concat @ W1^T + b1), MFMA split-fp16 ----
        {
            f32x4 acc[2][4];
            #pragma unroll
            for (int i = 0; i < 4; ++i) {
                float bi = b1p[l * 256 + (4 * w + i) * 16 + q];
                f32x4 bv = {bi, bi, bi, bi};
                acc[0][i] = bv; acc[1][i] = bv;
            }
            #pragma unroll 1
            for (int ks = 0; ks < KS1; ++ks) {
                f16x8 ah[2], al[2];
                #pragma unroll
                for (int m = 0; m < 2; ++m) {
                    ah[m] = ldfrag(&aT_hi[m * 16 + q][ks * 32 + h * 8]);
                    al[m] = ldfrag(&aT_lo[m * 16 + q][ks * 32 + h * 8]);
                }
                #pragma unroll
                for (int i = 0; i < 4; ++i) {
                    size_t off = ((((size_t)l * NT1 + 4 * w + i) * KS1 + ks) * 64 + lane) * 8;
                    f16x8 bh = ldfrag(W1Fhi + off);
                    f16x8 bl = ldfrag(W1Flo + off);
                    #pragma unroll
                    for (int m = 0; m < 2; ++m) {
                        acc[m][i] = MFMA(ah[m], bh, acc[m][i]);
                        acc[m][i] = MFMA(ah[m], bl, acc[m][i]);
                        acc[m][i] = MFMA(al[m], bh, acc[m][i]);
                    }
                }
            }
            #pragma unroll
            for (int m = 0; m < 2; ++m)
                #pragma unroll
                for (int i = 0; i < 4; ++i) {
                    int col = (4 * w + i) * 16 + q;
                    #pragma unroll
                    for (int reg = 0; reg < 4; ++reg) {
                        int row = m * 16 + 4 * h + reg;
                        float zv = fmaxf(acc[m][i][reg], 0.f);
                        splitf(zv, zT_hi[row][col], zT_lo[row][col]);
                    }
                }
        }
        __syncthreads();

        // ---- phase C : dtt/dv GEMM + state update ----
        {
            const float kap = kappa[l];
            const float inv = 1.0f / fabsf(kap);
            f32x4 acc[2][2];   // [ti][m]
            #pragma unroll
            for (int ti = 0; ti < 2; ++ti) {
                float bi = (ti < nt_cnt) ? b23p[l * 96 + (nt0 + ti) * 16 + q] : 0.f;
                f32x4 bv = {bi, bi, bi, bi};
                acc[ti][0] = bv; acc[ti][1] = bv;
            }
            #pragma unroll 1
            for (int ks = 0; ks < KS2; ++ks) {
                f16x8 ah[2], al[2];
                #pragma unroll
                for (int m = 0; m < 2; ++m) {
                    ah[m] = ldfrag(&zT_hi[m * 16 + q][ks * 32 + h * 8]);
                    al[m] = ldfrag(&zT_lo[m * 16 + q][ks * 32 + h * 8]);
                }
                for (int ti = 0; ti < nt_cnt; ++ti) {
                    size_t off = ((((size_t)l * NT2 + nt0 + ti) * KS2 + ks) * 64 + lane) * 8;
                    f16x8 bh = ldfrag(W23Fhi + off);
                    f16x8 bl = ldfrag(W23Flo + off);
                    #pragma unroll
                    for (int m = 0; m < 2; ++m) {
                        acc[ti][m] = MFMA(ah[m], bh, acc[ti][m]);
                        acc[ti][m] = MFMA(ah[m], bl, acc[ti][m]);
                        acc[ti][m] = MFMA(al[m], bh, acc[ti][m]);
                    }
                }
            }
            for (int ti = 0; ti < nt_cnt; ++ti) {
                const int col = (nt0 + ti) * 16 + q;
                const bool isT = col < 30;
                const bool isV = (col >= 30) & (col < 90);
                #pragma unroll
                for (int m = 0; m < 2; ++m)
                    #pragma unroll
                    for (int reg = 0; reg < 4; ++reg) {
                        float s2 = st[ti][m][reg] + acc[ti][m][reg];
                        int row = m * 16 + 4 * h + reg;
                        if (isT) {
                            st[ti][m][reg] = s2;
                            float tn = -1.0f + fmaxf(s2 + kap, 0.f) * inv - fmaxf(s2 - kap, 0.f) * inv;
                            tOut[row][col] = tn;
                            splitf(tn, aT_hi[row][90 + col], aT_lo[row][90 + col]);
                        } else if (isV) {
                            st[ti][m][reg] = s2;
                            splitf(s2, aT_hi[row][col], aT_lo[row][col]);
                        }
                    }
            }
        }
        __syncthreads();
    }

    // final output layer 89
    if (tid < 240) {
        f32x4 o;
        int e = tid * 4;
        #pragma unroll
        for (int i = 0; i < 4; ++i) {
            int ee = e + i, r = ee / 30, k2 = ee - 30 * r;
            o[i] = tOut[r][k2];
        }
        __builtin_nontemporal_store(o, (f32x4*)(out + ((size_t)(NLAYER - 1) * BB + b0) * KK + e));
    }
}

extern "C" void kernel_launch(void* const* d_in, const int* in_sizes, int n_in,
                              void* d_out, int out_size, void* d_ws, size_t ws_size,
                              hipStream_t stream) {
    const float* Hr = (const float*)d_in[0];
    const float* HH = (const float*)d_in[1];
    const float* W1 = (const float*)d_in[2];
    const float* b1 = (const float*)d_in[3];
    const float* W2 = (const float*)d_in[4];
    const float* b2 = (const float*)d_in[5];
    const float* W3 = (const float*)d_in[6];
    const float* b3 = (const float*)d_in[7];
    const float* kp = (const float*)d_in[8];
    float* out = (float*)d_out;

    if (ws_size < WS_NEEDED) return;  // workspace too small (not expected)

    u16* W1Fhi  = (u16*)d_ws;
    u16* W1Flo  = W1Fhi + SZ1;
    u16* W23Fhi = W1Flo + SZ1;
    u16* W23Flo = W23Fhi + SZ23;
    float* b1p  = (float*)(W23Flo + SZ23);
    float* b23p = b1p + NLAYER * 256;

    prep<<<dim3((SZ1 + 255) / 256), dim3(256), 0, stream>>>(
        W1, W2, W3, b1, b2, b3, W1Fhi, W1Flo, W23Fhi, W23Flo, b1p, b23p);
    detnet_kernel<<<dim3(NBLK), dim3(256), 0, stream>>>(
        Hr, HH, kp, W1Fhi, W1Flo, W23Fhi, W23Flo, b1p, b23p, out);
}

// Round 5
// 1142.903 us; speedup vs baseline: 4.8337x; 2.0702x over previous
//
#include <hip/hip_runtime.h>

typedef unsigned short u16;
typedef float    f32x4  __attribute__((ext_vector_type(4)));
typedef _Float16 f16x8  __attribute__((ext_vector_type(8)));
typedef short    short8 __attribute__((ext_vector_type(8)));

#define BB 16384
#define KK 30
#define NLAYER 90
#define ROWS 32
#define NBLK (BB / ROWS)
#define THREADS 512

#define NT1 16        // phase-B N-tiles (240 -> 256 padded; tile 15 zero)
#define KS1 5         // phase-B K-steps (150 -> 160 padded)
#define NT2 6         // phase-C N-tiles (90 -> 96 padded)
#define KS2 8         // phase-C K-steps (240 -> 256 padded)

#define SZ1  (NLAYER * NT1 * KS1 * 512)   // u16 per plane
#define SZ23 (NLAYER * NT2 * KS2 * 512)   // u16 per plane
#define WS_NEEDED ((size_t)4 * (SZ1 + SZ23) + (size_t)4 * (NLAYER * 256 + NLAYER * 96))

#define A_STRIDE 168   // 160 k + 8 pad (u16)
#define Z_STRIDE 264   // 256 k + 8 pad (u16)
#define TO_STRIDE 33

#define MFMA(a, b, c) __builtin_amdgcn_mfma_f32_16x16x32_f16((a), (b), (c), 0, 0, 0)

__device__ __forceinline__ void splitf(float x, u16& hi, u16& lo) {
    _Float16 h = (_Float16)x;
    _Float16 l = (_Float16)(x - (float)h);
    hi = __builtin_bit_cast(u16, h);
    lo = __builtin_bit_cast(u16, l);
}
__device__ __forceinline__ f16x8 ldfrag(const u16* p) {
    return __builtin_bit_cast(f16x8, *(const short8*)p);
}

// ---------------- prep: weights -> MFMA fragment layout (split fp16) -------
__global__ void prep(const float* __restrict__ W1, const float* __restrict__ W2,
                     const float* __restrict__ W3, const float* __restrict__ b1,
                     const float* __restrict__ b2, const float* __restrict__ b3,
                     u16* __restrict__ W1Fhi, u16* __restrict__ W1Flo,
                     u16* __restrict__ W23Fhi, u16* __restrict__ W23Flo,
                     float* __restrict__ b1p, float* __restrict__ b23p)
{
    int idx = blockIdx.x * 256 + threadIdx.x;
    if (idx < SZ1) {
        int j = idx & 7, lane = (idx >> 3) & 63;
        int r = idx >> 9, ks = r % 5; r /= 5;
        int nt = r % 16, l = r / 16;
        int k = ks * 32 + (lane >> 4) * 8 + j;
        int n = nt * 16 + (lane & 15);
        float wv = (k < 150 && n < 240) ? W1[((size_t)l * 240 + n) * 150 + k] : 0.f;
        splitf(wv, W1Fhi[idx], W1Flo[idx]);
    }
    if (idx < SZ23) {
        int j = idx & 7, lane = (idx >> 3) & 63;
        int r = idx >> 9, ks = r % 8; r /= 8;
        int nt = r % 6, l = r / 6;
        int k = ks * 32 + (lane >> 4) * 8 + j;
        int n = nt * 16 + (lane & 15);
        float wv = 0.f;
        if (k < 240) {
            if (n < 30)      wv = W2[((size_t)l * 30 + n) * 240 + k];
            else if (n < 90) wv = W3[((size_t)l * 60 + (n - 30)) * 240 + k];
        }
        splitf(wv, W23Fhi[idx], W23Flo[idx]);
    }
    if (idx < NLAYER * 256) {
        int l = idx >> 8, c = idx & 255;
        b1p[idx] = (c < 240) ? b1[l * 240 + c] : 0.f;
    }
    if (idx < NLAYER * 96) {
        int l = idx / 96, c = idx % 96;
        b23p[idx] = (c < 30) ? b2[l * 30 + c] : (c < 90 ? b3[l * 60 + (c - 30)] : 0.f);
    }
}

// ---------------- main persistent kernel (8 waves / block) ------------------
// concat LDS cols: 0..29 Hr | 30..89 v | 90..119 t | 120..149 tH | 150..159 zero
__global__ __launch_bounds__(THREADS, 4)
void detnet_kernel(const float* __restrict__ Hr, const float* __restrict__ HH,
                   const float* __restrict__ kappa,
                   const u16* __restrict__ W1Fhi, const u16* __restrict__ W1Flo,
                   const u16* __restrict__ W23Fhi, const u16* __restrict__ W23Flo,
                   const float* __restrict__ b1p, const float* __restrict__ b23p,
                   float* __restrict__ out)
{
    __shared__ u16 aT_hi[ROWS][A_STRIDE], aT_lo[ROWS][A_STRIDE];
    __shared__ u16 zT_hi[ROWS][Z_STRIDE], zT_lo[ROWS][Z_STRIDE];
    __shared__ float tOut[ROWS][TO_STRIDE];

    const int tid  = threadIdx.x;
    const int b0   = blockIdx.x * ROWS;
    const int w    = tid >> 6;       // 0..7
    const int lane = tid & 63;
    const int h    = lane >> 4;
    const int q    = lane & 15;

    // phase-C persistent state (waves 0..5 only): [m][reg]
    float st[2][4];
    #pragma unroll
    for (int m = 0; m < 2; ++m)
        #pragma unroll
        for (int r = 0; r < 4; ++r) st[m][r] = 0.f;

    // ---- init LDS ----
    for (int i = tid; i < ROWS * A_STRIDE; i += THREADS) { (&aT_hi[0][0])[i] = 0; (&aT_lo[0][0])[i] = 0; }
    for (int i = tid; i < ROWS * Z_STRIDE; i += THREADS) { (&zT_hi[0][0])[i] = 0; (&zT_lo[0][0])[i] = 0; }
    for (int i = tid; i < ROWS * TO_STRIDE; i += THREADS) (&tOut[0][0])[i] = 0.f;
    __syncthreads();
    for (int i = tid; i < ROWS * KK; i += THREADS) {
        int r = i / KK, k = i - r * KK;
        splitf(Hr[(size_t)(b0 + r) * KK + k], aT_hi[r][k], aT_lo[r][k]);
    }
    __syncthreads();

    for (int l = 0; l < NLAYER; ++l) {
        // ---- phase D (prev layer): NT store of t ----
        if (l > 0 && tid < 240) {
            f32x4 o;
            int e = tid * 4;
            #pragma unroll
            for (int i = 0; i < 4; ++i) {
                int ee = e + i, r = ee / 30, k2 = ee - 30 * r;
                o[i] = tOut[r][k2];
            }
            __builtin_nontemporal_store(o, (f32x4*)(out + ((size_t)(l - 1) * BB + b0) * KK + e));
        }

        // ---- phase A : tH = t . HH (fp32 VALU), split-write to aT ----
        if (l > 0) {
            const int r = tid >> 4, s = tid & 15;   // 32 rows x 16 col-pairs
            if (s < 15) {
                const float* hh = HH + (size_t)(b0 + r) * (KK * KK) + 2 * s;
                float a0 = 0.f, a1 = 0.f;
                #pragma unroll 6
                for (int k = 0; k < KK; ++k) {
                    float tk = tOut[r][k];
                    float2 u = *(const float2*)(hh + k * KK);
                    a0 += tk * u.x; a1 += tk * u.y;
                }
                u16 h0, l0, h1, l1;
                splitf(a0, h0, l0); splitf(a1, h1, l1);
                *(unsigned int*)&aT_hi[r][120 + 2 * s] = (unsigned int)h0 | ((unsigned int)h1 << 16);
                *(unsigned int*)&aT_lo[r][120 + 2 * s] = (unsigned int)l0 | ((unsigned int)l1 << 16);
            }
        }
        __syncthreads();

        // ---- phase B : z = relu(concat @ W1^T + b1), 2 tiles per wave ----
        {
            f32x4 acc[2][2];   // [i][m]
            #pragma unroll
            for (int i = 0; i < 2; ++i) {
                float bi = b1p[l * 256 + (2 * w + i) * 16 + q];
                f32x4 bv = {bi, bi, bi, bi};
                acc[i][0] = bv; acc[i][1] = bv;
            }
            #pragma unroll 2
            for (int ks = 0; ks < KS1; ++ks) {
                f16x8 ah[2], al[2];
                #pragma unroll
                for (int m = 0; m < 2; ++m) {
                    ah[m] = ldfrag(&aT_hi[m * 16 + q][ks * 32 + h * 8]);
                    al[m] = ldfrag(&aT_lo[m * 16 + q][ks * 32 + h * 8]);
                }
                #pragma unroll
                for (int i = 0; i < 2; ++i) {
                    size_t off = ((((size_t)l * NT1 + 2 * w + i) * KS1 + ks) * 64 + lane) * 8;
                    f16x8 bh = ldfrag(W1Fhi + off);
                    f16x8 bl = ldfrag(W1Flo + off);
                    #pragma unroll
                    for (int m = 0; m < 2; ++m) {
                        acc[i][m] = MFMA(ah[m], bh, acc[i][m]);
                        acc[i][m] = MFMA(ah[m], bl, acc[i][m]);
                        acc[i][m] = MFMA(al[m], bh, acc[i][m]);
                    }
                }
            }
            #pragma unroll
            for (int i = 0; i < 2; ++i)
                #pragma unroll
                for (int m = 0; m < 2; ++m) {
                    int col = (2 * w + i) * 16 + q;
                    #pragma unroll
                    for (int reg = 0; reg < 4; ++reg) {
                        int row = m * 16 + 4 * h + reg;
                        float zv = fmaxf(acc[i][m][reg], 0.f);
                        splitf(zv, zT_hi[row][col], zT_lo[row][col]);
                    }
                }
        }
        __syncthreads();

        // ---- phase C : dtt/dv GEMM + state update (waves 0..5) ----
        if (w < 6) {
            const float kap = kappa[l];
            const float inv = 1.0f / fabsf(kap);
            f32x4 acc[2];
            {
                float bi = b23p[l * 96 + w * 16 + q];
                f32x4 bv = {bi, bi, bi, bi};
                acc[0] = bv; acc[1] = bv;
            }
            #pragma unroll 2
            for (int ks = 0; ks < KS2; ++ks) {
                f16x8 ah[2], al[2];
                #pragma unroll
                for (int m = 0; m < 2; ++m) {
                    ah[m] = ldfrag(&zT_hi[m * 16 + q][ks * 32 + h * 8]);
                    al[m] = ldfrag(&zT_lo[m * 16 + q][ks * 32 + h * 8]);
                }
                size_t off = ((((size_t)l * NT2 + w) * KS2 + ks) * 64 + lane) * 8;
                f16x8 bh = ldfrag(W23Fhi + off);
                f16x8 bl = ldfrag(W23Flo + off);
                #pragma unroll
                for (int m = 0; m < 2; ++m) {
                    acc[m] = MFMA(ah[m], bh, acc[m]);
                    acc[m] = MFMA(ah[m], bl, acc[m]);
                    acc[m] = MFMA(al[m], bh, acc[m]);
                }
            }
            const int col = w * 16 + q;
            const bool isT = col < 30;
            const bool isV = (col >= 30) & (col < 90);
            #pragma unroll
            for (int m = 0; m < 2; ++m)
                #pragma unroll
                for (int reg = 0; reg < 4; ++reg) {
                    float s2 = st[m][reg] + acc[m][reg];
                    int row = m * 16 + 4 * h + reg;
                    if (isT) {
                        st[m][reg] = s2;
                        float tn = -1.0f + fmaxf(s2 + kap, 0.f) * inv - fmaxf(s2 - kap, 0.f) * inv;
                        tOut[row][col] = tn;
                        splitf(tn, aT_hi[row][90 + col], aT_lo[row][90 + col]);
                    } else if (isV) {
                        st[m][reg] = s2;
                        splitf(s2, aT_hi[row][col], aT_lo[row][col]);
                    }
                }
        }
        __syncthreads();
    }

    // final output layer 89
    if (tid < 240) {
        f32x4 o;
        int e = tid * 4;
        #pragma unroll
        for (int i = 0; i < 4; ++i) {
            int ee = e + i, r = ee / 30, k2 = ee - 30 * r;
            o[i] = tOut[r][k2];
        }
        __builtin_nontemporal_store(o, (f32x4*)(out + ((size_t)(NLAYER - 1) * BB + b0) * KK + e));
    }
}

extern "C" void kernel_launch(void* const* d_in, const int* in_sizes, int n_in,
                              void* d_out, int out_size, void* d_ws, size_t ws_size,
                              hipStream_t stream) {
    const float* Hr = (const float*)d_in[0];
    const float* HH = (const float*)d_in[1];
    const float* W1 = (const float*)d_in[2];
    const float* b1 = (const float*)d_in[3];
    const float* W2 = (const float*)d_in[4];
    const float* b2 = (const float*)d_in[5];
    const float* W3 = (const float*)d_in[6];
    const float* b3 = (const float*)d_in[7];
    const float* kp = (const float*)d_in[8];
    float* out = (float*)d_out;

    if (ws_size < WS_NEEDED) return;

    u16* W1Fhi  = (u16*)d_ws;
    u16* W1Flo  = W1Fhi + SZ1;
    u16* W23Fhi = W1Flo + SZ1;
    u16* W23Flo = W23Fhi + SZ23;
    float* b1p  = (float*)(W23Flo + SZ23);
    float* b23p = b1p + NLAYER * 256;

    prep<<<dim3((SZ1 + 255) / 256), dim3(256), 0, stream>>>(
        W1, W2, W3, b1, b2, b3, W1Fhi, W1Flo, W23Fhi, W23Flo, b1p, b23p);
    detnet_kernel<<<dim3(NBLK), dim3(THREADS), 0, stream>>>(
        Hr, HH, kp, W1Fhi, W1Flo, W23Fhi, W23Flo, b1p, b23p, out);
}

// Round 6
// 843.225 us; speedup vs baseline: 6.5516x; 1.3554x over previous
//
#include <hip/hip_runtime.h>

typedef unsigned short u16;
typedef float    f32x4  __attribute__((ext_vector_type(4)));
typedef _Float16 f16x8  __attribute__((ext_vector_type(8)));
typedef short    short8 __attribute__((ext_vector_type(8)));

#define BB 16384
#define KK 30
#define NLAYER 90
#define ROWS 32
#define NBLK (BB / ROWS)
#define THREADS 512

#define NT1 16        // phase-B N-tiles (240 -> 256 padded; tile 15 zero)
#define KS1 5         // phase-B K-steps (150 -> 160 padded)
#define NT2 6         // phase-C N-tiles (90 -> 96 padded)
#define KS2 8         // phase-C K-steps (240 -> 256 padded)

#define SZ1  (NLAYER * NT1 * KS1 * 512)   // u16 per plane
#define SZ23 (NLAYER * NT2 * KS2 * 512)   // u16 per plane
#define WS_NEEDED ((size_t)4 * (SZ1 + SZ23) + (size_t)4 * (NLAYER * 256 + NLAYER * 96))

#define A_STRIDE 168   // 160 k + 8 pad (u16)
#define Z_STRIDE 264   // 256 k + 8 pad (u16)
#define TO_STRIDE 33

#define MFMA(a, b, c) __builtin_amdgcn_mfma_f32_16x16x32_f16((a), (b), (c), 0, 0, 0)

__device__ __forceinline__ void splitf(float x, u16& hi, u16& lo) {
    _Float16 h = (_Float16)x;
    _Float16 l = (_Float16)(x - (float)h);
    hi = __builtin_bit_cast(u16, h);
    lo = __builtin_bit_cast(u16, l);
}
__device__ __forceinline__ f16x8 ldfrag(const u16* p) {
    return __builtin_bit_cast(f16x8, *(const short8*)p);
}

// ---------------- prep: weights -> MFMA fragment layout (split fp16) -------
__global__ void prep(const float* __restrict__ W1, const float* __restrict__ W2,
                     const float* __restrict__ W3, const float* __restrict__ b1,
                     const float* __restrict__ b2, const float* __restrict__ b3,
                     u16* __restrict__ W1Fhi, u16* __restrict__ W1Flo,
                     u16* __restrict__ W23Fhi, u16* __restrict__ W23Flo,
                     float* __restrict__ b1p, float* __restrict__ b23p)
{
    int idx = blockIdx.x * 256 + threadIdx.x;
    if (idx < SZ1) {
        int j = idx & 7, lane = (idx >> 3) & 63;
        int r = idx >> 9, ks = r % 5; r /= 5;
        int nt = r % 16, l = r / 16;
        int k = ks * 32 + (lane >> 4) * 8 + j;
        int n = nt * 16 + (lane & 15);
        float wv = (k < 150 && n < 240) ? W1[((size_t)l * 240 + n) * 150 + k] : 0.f;
        splitf(wv, W1Fhi[idx], W1Flo[idx]);
    }
    if (idx < SZ23) {
        int j = idx & 7, lane = (idx >> 3) & 63;
        int r = idx >> 9, ks = r % 8; r /= 8;
        int nt = r % 6, l = r / 6;
        int k = ks * 32 + (lane >> 4) * 8 + j;
        int n = nt * 16 + (lane & 15);
        float wv = 0.f;
        if (k < 240) {
            if (n < 30)      wv = W2[((size_t)l * 30 + n) * 240 + k];
            else if (n < 90) wv = W3[((size_t)l * 60 + (n - 30)) * 240 + k];
        }
        splitf(wv, W23Fhi[idx], W23Flo[idx]);
    }
    if (idx < NLAYER * 256) {
        int l = idx >> 8, c = idx & 255;
        b1p[idx] = (c < 240) ? b1[l * 240 + c] : 0.f;
    }
    if (idx < NLAYER * 96) {
        int l = idx / 96, c = idx % 96;
        b23p[idx] = (c < 30) ? b2[l * 30 + c] : (c < 90 ? b3[l * 60 + (c - 30)] : 0.f);
    }
}

// ---------------- main persistent kernel (8 waves / block) ------------------
// concat LDS cols: 0..29 Hr | 30..89 v | 90..119 t | 120..149 tH | 150..159 zero
__global__ __launch_bounds__(THREADS, 4)
void detnet_kernel(const float* __restrict__ Hr, const float* __restrict__ HH,
                   const float* __restrict__ kappa,
                   const u16* __restrict__ W1Fhi, const u16* __restrict__ W1Flo,
                   const u16* __restrict__ W23Fhi, const u16* __restrict__ W23Flo,
                   const float* __restrict__ b1p, const float* __restrict__ b23p,
                   float* __restrict__ out)
{
    __shared__ u16 aT_hi[ROWS][A_STRIDE], aT_lo[ROWS][A_STRIDE];
    __shared__ u16 zT_hi[ROWS][Z_STRIDE], zT_lo[ROWS][Z_STRIDE];
    __shared__ float tOut[ROWS][TO_STRIDE];

    const int tid  = threadIdx.x;
    const int b0   = blockIdx.x * ROWS;
    const int w    = tid >> 6;       // 0..7
    const int lane = tid & 63;
    const int h    = lane >> 4;
    const int q    = lane & 15;

    // phase-A mapping + persistent HH registers (HH is layer-invariant:
    // each thread owns 2 columns x 30 k = 30 float2 = 60 VGPRs, loaded once)
    const int ra = tid >> 4;         // 0..31
    const int sa = tid & 15;         // col pair 2sa, 2sa+1 (sa<15 active)
    float2 hreg[KK];
    if (sa < 15) {
        const float* hh = HH + (size_t)(b0 + ra) * (KK * KK) + 2 * sa;
        #pragma unroll
        for (int k = 0; k < KK; ++k) hreg[k] = *(const float2*)(hh + k * KK);
    } else {
        #pragma unroll
        for (int k = 0; k < KK; ++k) hreg[k] = make_float2(0.f, 0.f);
    }

    // phase-C persistent state (waves 0..5 only): [m][reg]
    float st[2][4];
    #pragma unroll
    for (int m = 0; m < 2; ++m)
        #pragma unroll
        for (int r = 0; r < 4; ++r) st[m][r] = 0.f;

    // ---- init LDS ----
    for (int i = tid; i < ROWS * A_STRIDE; i += THREADS) { (&aT_hi[0][0])[i] = 0; (&aT_lo[0][0])[i] = 0; }
    for (int i = tid; i < ROWS * Z_STRIDE; i += THREADS) { (&zT_hi[0][0])[i] = 0; (&zT_lo[0][0])[i] = 0; }
    for (int i = tid; i < ROWS * TO_STRIDE; i += THREADS) (&tOut[0][0])[i] = 0.f;
    __syncthreads();
    for (int i = tid; i < ROWS * KK; i += THREADS) {
        int r = i / KK, k = i - r * KK;
        splitf(Hr[(size_t)(b0 + r) * KK + k], aT_hi[r][k], aT_lo[r][k]);
    }
    __syncthreads();

    for (int l = 0; l < NLAYER; ++l) {
        // ---- phase D (prev layer): NT store of t ----
        if (l > 0 && tid < 240) {
            f32x4 o;
            int e = tid * 4;
            #pragma unroll
            for (int i = 0; i < 4; ++i) {
                int ee = e + i, r = ee / 30, k2 = ee - 30 * r;
                o[i] = tOut[r][k2];
            }
            __builtin_nontemporal_store(o, (f32x4*)(out + ((size_t)(l - 1) * BB + b0) * KK + e));
        }

        // ---- phase A : tH = t . HH, pure register FMA ----
        if (l > 0 && sa < 15) {
            float a0 = 0.f, a1 = 0.f;
            #pragma unroll
            for (int k = 0; k < KK; ++k) {
                float tk = tOut[ra][k];
                a0 += tk * hreg[k].x;
                a1 += tk * hreg[k].y;
            }
            u16 h0, l0, h1, l1;
            splitf(a0, h0, l0); splitf(a1, h1, l1);
            *(unsigned int*)&aT_hi[ra][120 + 2 * sa] = (unsigned int)h0 | ((unsigned int)h1 << 16);
            *(unsigned int*)&aT_lo[ra][120 + 2 * sa] = (unsigned int)l0 | ((unsigned int)l1 << 16);
        }
        __syncthreads();

        // ---- phase B : z = relu(concat @ W1^T + b1), 2 tiles per wave ----
        {
            f32x4 acc[2][2];   // [i][m]
            #pragma unroll
            for (int i = 0; i < 2; ++i) {
                float bi = b1p[l * 256 + (2 * w + i) * 16 + q];
                f32x4 bv = {bi, bi, bi, bi};
                acc[i][0] = bv; acc[i][1] = bv;
            }
            #pragma unroll 2
            for (int ks = 0; ks < KS1; ++ks) {
                f16x8 ah[2], al[2];
                #pragma unroll
                for (int m = 0; m < 2; ++m) {
                    ah[m] = ldfrag(&aT_hi[m * 16 + q][ks * 32 + h * 8]);
                    al[m] = ldfrag(&aT_lo[m * 16 + q][ks * 32 + h * 8]);
                }
                #pragma unroll
                for (int i = 0; i < 2; ++i) {
                    size_t off = ((((size_t)l * NT1 + 2 * w + i) * KS1 + ks) * 64 + lane) * 8;
                    f16x8 bh = ldfrag(W1Fhi + off);
                    f16x8 bl = ldfrag(W1Flo + off);
                    #pragma unroll
                    for (int m = 0; m < 2; ++m) {
                        acc[i][m] = MFMA(ah[m], bh, acc[i][m]);
                        acc[i][m] = MFMA(ah[m], bl, acc[i][m]);
                        acc[i][m] = MFMA(al[m], bh, acc[i][m]);
                    }
                }
            }
            #pragma unroll
            for (int i = 0; i < 2; ++i)
                #pragma unroll
                for (int m = 0; m < 2; ++m) {
                    int col = (2 * w + i) * 16 + q;
                    #pragma unroll
                    for (int reg = 0; reg < 4; ++reg) {
                        int row = m * 16 + 4 * h + reg;
                        float zv = fmaxf(acc[i][m][reg], 0.f);
                        splitf(zv, zT_hi[row][col], zT_lo[row][col]);
                    }
                }
        }
        __syncthreads();

        // ---- phase C : dtt/dv GEMM + state update (waves 0..5) ----
        if (w < 6) {
            const float kap = kappa[l];
            const float inv = 1.0f / fabsf(kap);
            f32x4 acc[2];
            {
                float bi = b23p[l * 96 + w * 16 + q];
                f32x4 bv = {bi, bi, bi, bi};
                acc[0] = bv; acc[1] = bv;
            }
            #pragma unroll 2
            for (int ks = 0; ks < KS2; ++ks) {
                f16x8 ah[2], al[2];
                #pragma unroll
                for (int m = 0; m < 2; ++m) {
                    ah[m] = ldfrag(&zT_hi[m * 16 + q][ks * 32 + h * 8]);
                    al[m] = ldfrag(&zT_lo[m * 16 + q][ks * 32 + h * 8]);
                }
                size_t off = ((((size_t)l * NT2 + w) * KS2 + ks) * 64 + lane) * 8;
                f16x8 bh = ldfrag(W23Fhi + off);
                f16x8 bl = ldfrag(W23Flo + off);
                #pragma unroll
                for (int m = 0; m < 2; ++m) {
                    acc[m] = MFMA(ah[m], bh, acc[m]);
                    acc[m] = MFMA(ah[m], bl, acc[m]);
                    acc[m] = MFMA(al[m], bh, acc[m]);
                }
            }
            const int col = w * 16 + q;
            const bool isT = col < 30;
            const bool isV = (col >= 30) & (col < 90);
            #pragma unroll
            for (int m = 0; m < 2; ++m)
                #pragma unroll
                for (int reg = 0; reg < 4; ++reg) {
                    float s2 = st[m][reg] + acc[m][reg];
                    int row = m * 16 + 4 * h + reg;
                    if (isT) {
                        st[m][reg] = s2;
                        float tn = -1.0f + fmaxf(s2 + kap, 0.f) * inv - fmaxf(s2 - kap, 0.f) * inv;
                        tOut[row][col] = tn;
                        splitf(tn, aT_hi[row][90 + col], aT_lo[row][90 + col]);
                    } else if (isV) {
                        st[m][reg] = s2;
                        splitf(s2, aT_hi[row][col], aT_lo[row][col]);
                    }
                }
        }
        __syncthreads();
    }

    // final output layer 89
    if (tid < 240) {
        f32x4 o;
        int e = tid * 4;
        #pragma unroll
        for (int i = 0; i < 4; ++i) {
            int ee = e + i, r = ee / 30, k2 = ee - 30 * r;
            o[i] = tOut[r][k2];
        }
        __builtin_nontemporal_store(o, (f32x4*)(out + ((size_t)(NLAYER - 1) * BB + b0) * KK + e));
    }
}

extern "C" void kernel_launch(void* const* d_in, const int* in_sizes, int n_in,
                              void* d_out, int out_size, void* d_ws, size_t ws_size,
                              hipStream_t stream) {
    const float* Hr = (const float*)d_in[0];
    const float* HH = (const float*)d_in[1];
    const float* W1 = (const float*)d_in[2];
    const float* b1 = (const float*)d_in[3];
    const float* W2 = (const float*)d_in[4];
    const float* b2 = (const float*)d_in[5];
    const float* W3 = (const float*)d_in[6];
    const float* b3 = (const float*)d_in[7];
    const float* kp = (const float*)d_in[8];
    float* out = (float*)d_out;

    if (ws_size < WS_NEEDED) return;

    u16* W1Fhi  = (u16*)d_ws;
    u16* W1Flo  = W1Fhi + SZ1;
    u16* W23Fhi = W1Flo + SZ1;
    u16* W23Flo = W23Fhi + SZ23;
    float* b1p  = (float*)(W23Flo + SZ23);
    float* b23p = b1p + NLAYER * 256;

    prep<<<dim3((SZ1 + 255) / 256), dim3(256), 0, stream>>>(
        W1, W2, W3, b1, b2, b3, W1Fhi, W1Flo, W23Fhi, W23Flo, b1p, b23p);
    detnet_kernel<<<dim3(NBLK), dim3(THREADS), 0, stream>>>(
        Hr, HH, kp, W1Fhi, W1Flo, W23Fhi, W23Flo, b1p, b23p, out);
}

// Round 8
// 759.164 us; speedup vs baseline: 7.2771x; 1.1107x over previous
//
#include <hip/hip_runtime.h>

typedef unsigned short u16;
typedef float    f32x4  __attribute__((ext_vector_type(4)));
typedef _Float16 f16x8  __attribute__((ext_vector_type(8)));
typedef short    short8 __attribute__((ext_vector_type(8)));

#define BB 16384
#define KK 30
#define NLAYER 90
#define ROWS 64
#define NBLK (BB / ROWS)     // 256 blocks = 1 per CU
#define THREADS 1024         // 16 waves

#define NT1 16        // phase-B N-tiles (240 -> 256 padded; tile 15 zero)
#define KS1 5         // phase-B K-steps (150 -> 160 padded)
#define NT2 6         // phase-C N-tiles (90 -> 96 padded)
#define KS2 8         // phase-C K-steps (240 -> 256 padded)

#define SZ1  (NLAYER * NT1 * KS1 * 512)   // u16 per plane
#define SZ23 (NLAYER * NT2 * KS2 * 512)   // u16 per plane
#define WS_NEEDED ((size_t)4 * (SZ1 + SZ23) + (size_t)4 * (NLAYER * 256 + NLAYER * 96))

#define A_STRIDE 168   // 160 k + 8 pad (u16)
#define Z_STRIDE 264   // 256 k + 8 pad (u16)
#define TO_STRIDE 33

#define MFMA(a, b, c) __builtin_amdgcn_mfma_f32_16x16x32_f16((a), (b), (c), 0, 0, 0)

__device__ __forceinline__ void splitf(float x, u16& hi, u16& lo) {
    _Float16 h = (_Float16)x;
    _Float16 l = (_Float16)(x - (float)h);
    hi = __builtin_bit_cast(u16, h);
    lo = __builtin_bit_cast(u16, l);
}
__device__ __forceinline__ f16x8 ldfrag(const u16* p) {
    return __builtin_bit_cast(f16x8, *(const short8*)p);
}

// ---------------- prep: weights -> MFMA fragment layout (split fp16) -------
__global__ void prep(const float* __restrict__ W1, const float* __restrict__ W2,
                     const float* __restrict__ W3, const float* __restrict__ b1,
                     const float* __restrict__ b2, const float* __restrict__ b3,
                     u16* __restrict__ W1Fhi, u16* __restrict__ W1Flo,
                     u16* __restrict__ W23Fhi, u16* __restrict__ W23Flo,
                     float* __restrict__ b1p, float* __restrict__ b23p)
{
    int idx = blockIdx.x * 256 + threadIdx.x;
    if (idx < SZ1) {
        int j = idx & 7, lane = (idx >> 3) & 63;
        int r = idx >> 9, ks = r % 5; r /= 5;
        int nt = r % 16, l = r / 16;
        int k = ks * 32 + (lane >> 4) * 8 + j;
        int n = nt * 16 + (lane & 15);
        float wv = (k < 150 && n < 240) ? W1[((size_t)l * 240 + n) * 150 + k] : 0.f;
        splitf(wv, W1Fhi[idx], W1Flo[idx]);
    }
    if (idx < SZ23) {
        int j = idx & 7, lane = (idx >> 3) & 63;
        int r = idx >> 9, ks = r % 8; r /= 8;
        int nt = r % 6, l = r / 6;
        int k = ks * 32 + (lane >> 4) * 8 + j;
        int n = nt * 16 + (lane & 15);
        float wv = 0.f;
        if (k < 240) {
            if (n < 30)      wv = W2[((size_t)l * 30 + n) * 240 + k];
            else if (n < 90) wv = W3[((size_t)l * 60 + (n - 30)) * 240 + k];
        }
        splitf(wv, W23Fhi[idx], W23Flo[idx]);
    }
    if (idx < NLAYER * 256) {
        int l = idx >> 8, c = idx & 255;
        b1p[idx] = (c < 240) ? b1[l * 240 + c] : 0.f;
    }
    if (idx < NLAYER * 96) {
        int l = idx / 96, c = idx % 96;
        b23p[idx] = (c < 30) ? b2[l * 30 + c] : (c < 90 ? b3[l * 60 + (c - 30)] : 0.f);
    }
}

// ---------------- main persistent kernel (16 waves, 64 rows / block) --------
// concat LDS cols: 0..29 Hr | 30..89 v | 90..119 t | 120..149 tH | 150..159 zero
__global__ __launch_bounds__(THREADS, 4)
void detnet_kernel(const float* __restrict__ Hr, const float* __restrict__ HH,
                   const float* __restrict__ kappa,
                   const u16* __restrict__ W1Fhi, const u16* __restrict__ W1Flo,
                   const u16* __restrict__ W23Fhi, const u16* __restrict__ W23Flo,
                   const float* __restrict__ b1p, const float* __restrict__ b23p,
                   float* __restrict__ out)
{
    __shared__ u16 aT_hi[ROWS][A_STRIDE], aT_lo[ROWS][A_STRIDE];
    __shared__ u16 zT_hi[ROWS][Z_STRIDE], zT_lo[ROWS][Z_STRIDE];
    __shared__ float tOut[ROWS][TO_STRIDE];

    const int tid  = threadIdx.x;
    const int b0   = blockIdx.x * ROWS;
    const int w    = tid >> 6;       // 0..15
    const int lane = tid & 63;
    const int h    = lane >> 4;
    const int q    = lane & 15;

    // phase-A mapping + persistent HH registers (layer-invariant):
    // thread -> (row ra, col pair 2sa,2sa+1); 64 rows x 16 = 1024 threads
    const int ra = tid >> 4;         // 0..63
    const int sa = tid & 15;         // sa<15 active
    float2 hreg[KK];
    if (sa < 15) {
        const float* hh = HH + (size_t)(b0 + ra) * (KK * KK) + 2 * sa;
        #pragma unroll
        for (int k = 0; k < KK; ++k) hreg[k] = *(const float2*)(hh + k * KK);
    } else {
        #pragma unroll
        for (int k = 0; k < KK; ++k) hreg[k] = make_float2(0.f, 0.f);
    }

    // phase-C mapping: waves 0..11 -> (nt, m-half); persistent state st[mm][reg]
    const int cnt = w >> 1;          // 0..5 (col tile)
    const int cmh = w & 1;           // m-half: m-tiles cmh*2, cmh*2+1
    float st[2][4];
    #pragma unroll
    for (int m = 0; m < 2; ++m)
        #pragma unroll
        for (int r = 0; r < 4; ++r) st[m][r] = 0.f;

    // ---- init LDS ----
    for (int i = tid; i < ROWS * A_STRIDE; i += THREADS) { (&aT_hi[0][0])[i] = 0; (&aT_lo[0][0])[i] = 0; }
    for (int i = tid; i < ROWS * Z_STRIDE; i += THREADS) { (&zT_hi[0][0])[i] = 0; (&zT_lo[0][0])[i] = 0; }
    for (int i = tid; i < ROWS * TO_STRIDE; i += THREADS) (&tOut[0][0])[i] = 0.f;
    __syncthreads();
    for (int i = tid; i < ROWS * KK; i += THREADS) {
        int r = i / KK, k = i - r * KK;
        splitf(Hr[(size_t)(b0 + r) * KK + k], aT_hi[r][k], aT_lo[r][k]);
    }
    __syncthreads();

    for (int l = 0; l < NLAYER; ++l) {
        // ---- phase D (prev layer): NT store of t ----
        if (l > 0 && tid < ROWS * KK / 4) {
            f32x4 o;
            int e = tid * 4;
            #pragma unroll
            for (int i = 0; i < 4; ++i) {
                int ee = e + i, r = ee / 30, k2 = ee - 30 * r;
                o[i] = tOut[r][k2];
            }
            __builtin_nontemporal_store(o, (f32x4*)(out + ((size_t)(l - 1) * BB + b0) * KK + e));
        }

        // ---- phase A : tH = t . HH, pure register FMA ----
        if (l > 0 && sa < 15) {
            float a0 = 0.f, a1 = 0.f;
            #pragma unroll
            for (int k = 0; k < KK; ++k) {
                float tk = tOut[ra][k];
                a0 += tk * hreg[k].x;
                a1 += tk * hreg[k].y;
            }
            u16 h0, l0, h1, l1;
            splitf(a0, h0, l0); splitf(a1, h1, l1);
            *(unsigned int*)&aT_hi[ra][120 + 2 * sa] = (unsigned int)h0 | ((unsigned int)h1 << 16);
            *(unsigned int*)&aT_lo[ra][120 + 2 * sa] = (unsigned int)l0 | ((unsigned int)l1 << 16);
        }
        __syncthreads();

        // ---- phase B : z = relu(concat @ W1^T + b1); 1 N-tile x 4 M-tiles/wave ----
        {
            f32x4 acc[4];
            {
                float bi = b1p[l * 256 + w * 16 + q];
                f32x4 bv = {bi, bi, bi, bi};
                #pragma unroll
                for (int m = 0; m < 4; ++m) acc[m] = bv;
            }
            #pragma unroll 2
            for (int ks = 0; ks < KS1; ++ks) {
                size_t off = ((((size_t)l * NT1 + w) * KS1 + ks) * 64 + lane) * 8;
                f16x8 bh = ldfrag(W1Fhi + off);
                f16x8 bl = ldfrag(W1Flo + off);
                #pragma unroll
                for (int m = 0; m < 4; ++m) {
                    f16x8 ah = ldfrag(&aT_hi[m * 16 + q][ks * 32 + h * 8]);
                    f16x8 al = ldfrag(&aT_lo[m * 16 + q][ks * 32 + h * 8]);
                    acc[m] = MFMA(ah, bh, acc[m]);
                    acc[m] = MFMA(ah, bl, acc[m]);
                    acc[m] = MFMA(al, bh, acc[m]);
                }
            }
            #pragma unroll
            for (int m = 0; m < 4; ++m) {
                int col = w * 16 + q;
                #pragma unroll
                for (int reg = 0; reg < 4; ++reg) {
                    int row = m * 16 + 4 * h + reg;
                    float zv = fmaxf(acc[m][reg], 0.f);
                    splitf(zv, zT_hi[row][col], zT_lo[row][col]);
                }
            }
        }
        __syncthreads();

        // ---- phase C : dtt/dv GEMM + state update (waves 0..11) ----
        if (w < 12) {
            const float kap = kappa[l];
            const float inv = 1.0f / fabsf(kap);
            f32x4 acc[2];
            {
                float bi = b23p[l * 96 + cnt * 16 + q];
                f32x4 bv = {bi, bi, bi, bi};
                acc[0] = bv; acc[1] = bv;
            }
            #pragma unroll 2
            for (int ks = 0; ks < KS2; ++ks) {
                size_t off = ((((size_t)l * NT2 + cnt) * KS2 + ks) * 64 + lane) * 8;
                f16x8 bh = ldfrag(W23Fhi + off);
                f16x8 bl = ldfrag(W23Flo + off);
                #pragma unroll
                for (int mm = 0; mm < 2; ++mm) {
                    f16x8 ah = ldfrag(&zT_hi[(cmh * 2 + mm) * 16 + q][ks * 32 + h * 8]);
                    f16x8 al = ldfrag(&zT_lo[(cmh * 2 + mm) * 16 + q][ks * 32 + h * 8]);
                    acc[mm] = MFMA(ah, bh, acc[mm]);
                    acc[mm] = MFMA(ah, bl, acc[mm]);
                    acc[mm] = MFMA(al, bh, acc[mm]);
                }
            }
            const int col = cnt * 16 + q;
            const bool isT = col < 30;
            const bool isV = (col >= 30) & (col < 90);
            #pragma unroll
            for (int mm = 0; mm < 2; ++mm)
                #pragma unroll
                for (int reg = 0; reg < 4; ++reg) {
                    float s2 = st[mm][reg] + acc[mm][reg];
                    int row = (cmh * 2 + mm) * 16 + 4 * h + reg;
                    if (isT) {
                        st[mm][reg] = s2;
                        float tn = -1.0f + fmaxf(s2 + kap, 0.f) * inv - fmaxf(s2 - kap, 0.f) * inv;
                        tOut[row][col] = tn;
                        splitf(tn, aT_hi[row][90 + col], aT_lo[row][90 + col]);
                    } else if (isV) {
                        st[mm][reg] = s2;
                        splitf(s2, aT_hi[row][col], aT_lo[row][col]);
                    }
                }
        }
        __syncthreads();
    }

    // final output layer 89
    if (tid < ROWS * KK / 4) {
        f32x4 o;
        int e = tid * 4;
        #pragma unroll
        for (int i = 0; i < 4; ++i) {
            int ee = e + i, r = ee / 30, k2 = ee - 30 * r;
            o[i] = tOut[r][k2];
        }
        __builtin_nontemporal_store(o, (f32x4*)(out + ((size_t)(NLAYER - 1) * BB + b0) * KK + e));
    }
}

extern "C" void kernel_launch(void* const* d_in, const int* in_sizes, int n_in,
                              void* d_out, int out_size, void* d_ws, size_t ws_size,
                              hipStream_t stream) {
    const float* Hr = (const float*)d_in[0];
    const float* HH = (const float*)d_in[1];
    const float* W1 = (const float*)d_in[2];
    const float* b1 = (const float*)d_in[3];
    const float* W2 = (const float*)d_in[4];
    const float* b2 = (const float*)d_in[5];
    const float* W3 = (const float*)d_in[6];
    const float* b3 = (const float*)d_in[7];
    const float* kp = (const float*)d_in[8];
    float* out = (float*)d_out;

    if (ws_size < WS_NEEDED) return;

    u16* W1Fhi  = (u16*)d_ws;
    u16* W1Flo  = W1Fhi + SZ1;
    u16* W23Fhi = W1Flo + SZ1;
    u16* W23Flo = W23Fhi + SZ23;
    float* b1p  = (float*)(W23Flo + SZ23);
    float* b23p = b1p + NLAYER * 256;

    prep<<<dim3((SZ1 + 255) / 256), dim3(256), 0, stream>>>(
        W1, W2, W3, b1, b2, b3, W1Fhi, W1Flo, W23Fhi, W23Flo, b1p, b23p);
    detnet_kernel<<<dim3(NBLK), dim3(THREADS), 0, stream>>>(
        Hr, HH, kp, W1Fhi, W1Flo, W23Fhi, W23Flo, b1p, b23p, out);
}